// Round 5
// baseline (980.063 us; speedup 1.0000x reference)
//
#include <hip/hip_runtime.h>
#include <hip/hip_bf16.h>
#include <math.h>

// Sizes fixed by the reference setup: B=512, F=512, max_depth=8 -> S=255 splits, N=511 nodes, NC=21.
#define BATCH 512
#define FDIM  512
#define NSPL  255
#define NNOD  511
#define NC    21

// NOTE (round-3 post-mortem): the scan's merge dynamics depend on EXACT
// bit-level ties (viol == 0.0 at freshly merged nodes). Any change that
// perturbs upstream bits (qsT, ga, agrp0) or duplicates f64 expressions
// (letting -ffp-contract=fast contract them differently) breaks the exact
// ties and blows the scan up to the full 512 iterations (863 us, round 3).
// This file keeps the validated bit-configuration (round 2/4). The ONLY
// change this round: __shfl_xor -> DPP/swizzle in k_scan, same butterfly
// stage order (16,8,4,2,1) => bit-identical sums, faster stages.

// ---------------------------------------------------------------------------
// Cross-lane helpers: exact lane-permutation equivalents of __shfl_xor.
// xor1: quad_perm [1,0,3,2]=0xB1; xor2: quad_perm [2,3,0,1]=0x4E
// xor4: row_shl:4 -> banks 1,3 ; row_shr:4 -> banks 0,2
// xor8: row_shl:8 -> banks 2,3 ; row_shr:8 -> banks 0,1
// xor16 (within each 32-half): ds_swizzle bit-mode 0x401F
// ---------------------------------------------------------------------------
__device__ __forceinline__ int i_xor1(int v) { return __builtin_amdgcn_update_dpp(v, v, 0xB1, 0xF, 0xF, false); }
__device__ __forceinline__ int i_xor2(int v) { return __builtin_amdgcn_update_dpp(v, v, 0x4E, 0xF, 0xF, false); }
__device__ __forceinline__ int i_xor4(int v) {
  int t = __builtin_amdgcn_update_dpp(v, v, 0x104, 0xF, 0xA, false);  // row_shl:4 -> lanes 4-7,12-15
  return __builtin_amdgcn_update_dpp(t, v, 0x114, 0xF, 0x5, false);   // row_shr:4 -> lanes 0-3,8-11
}
__device__ __forceinline__ int i_xor8(int v) {
  int t = __builtin_amdgcn_update_dpp(v, v, 0x108, 0xF, 0xC, false);  // row_shl:8 -> lanes 8-15
  return __builtin_amdgcn_update_dpp(t, v, 0x118, 0xF, 0x3, false);   // row_shr:8 -> lanes 0-7
}
__device__ __forceinline__ int i_xor16(int v) { return __builtin_amdgcn_ds_swizzle(v, 0x401F); }

#define D_SHUF(NAME, FI)                                                     \
__device__ __forceinline__ double NAME(double v) {                           \
  int2 a = __builtin_bit_cast(int2, v);                                      \
  a.x = FI(a.x); a.y = FI(a.y);                                              \
  return __builtin_bit_cast(double, a);                                      \
}
D_SHUF(d_xor1, i_xor1)
D_SHUF(d_xor2, i_xor2)
D_SHUF(d_xor4, i_xor4)
D_SHUF(d_xor8, i_xor8)
D_SHUF(d_xor16, i_xor16)

// ---------------------------------------------------------------------------
// Kernel 1: tiled split-K GEMM. partial[z][s][b] = sum_{f in chunk z} W[f,s]*x[b,f]
// ---------------------------------------------------------------------------
__global__ __launch_bounds__(256) void k_qgemm(const float* __restrict__ x,
                                               const float* __restrict__ W,
                                               float* __restrict__ partial,
                                               int fpc) {
  __shared__ float Ws[64 * 68];
  __shared__ float xT[64 * 68];
  const int tid = threadIdx.x;
  const int s0 = blockIdx.x * 64;
  const int b0 = blockIdx.y * 64;
  const int f0 = blockIdx.z * fpc;
  const int sx = tid & 15;
  const int by = tid >> 4;
  float acc[4][4];
#pragma unroll
  for (int i = 0; i < 4; ++i)
#pragma unroll
    for (int j = 0; j < 4; ++j) acc[i][j] = 0.f;

  for (int fc = f0; fc < f0 + fpc; fc += 64) {
    {
      int si = tid & 63, fr = tid >> 6;
#pragma unroll
      for (int r = 0; r < 16; ++r) {
        int fi = fr + r * 4;
        int s = s0 + si;
        Ws[fi * 68 + si] = (s < NSPL) ? W[(fc + fi) * NSPL + s] : 0.f;
      }
      int j = tid & 63, ir = tid >> 6;
#pragma unroll
      for (int r = 0; r < 16; ++r) {
        int i = ir + r * 4;
        xT[j * 68 + i] = x[(b0 + i) * FDIM + (fc + j)];
      }
    }
    __syncthreads();
#pragma unroll 8
    for (int f = 0; f < 64; ++f) {
      float4 av = *(const float4*)&Ws[f * 68 + sx * 4];
      float4 xv = *(const float4*)&xT[f * 68 + by * 4];
      const float a4[4] = {av.x, av.y, av.z, av.w};
      const float x4[4] = {xv.x, xv.y, xv.z, xv.w};
#pragma unroll
      for (int i = 0; i < 4; ++i)
#pragma unroll
        for (int j = 0; j < 4; ++j) acc[i][j] += a4[i] * x4[j];
    }
    __syncthreads();
  }

  float* pout = partial + (size_t)blockIdx.z * (256 * BATCH);
#pragma unroll
  for (int i = 0; i < 4; ++i) {
    int s = s0 + sx * 4 + i;
    if (s < NSPL) {
      float4 v = make_float4(acc[i][0], acc[i][1], acc[i][2], acc[i][3]);
      *(float4*)&pout[s * BATCH + b0 + by * 4] = v;
    }
  }
}

// Reduce: qsT[s][b] = (sum_z partial[z][s][b], ascending z) + bias[s]
__global__ __launch_bounds__(256) void k_qreduce(const float* __restrict__ partial,
                                                 const float* __restrict__ bias,
                                                 float* __restrict__ qsT, int n) {
  int idx = blockIdx.x * 256 + threadIdx.x;
  if (idx >= NSPL * BATCH) return;
  int s = idx >> 9;
  float v = 0.f;
  for (int c = 0; c < n; ++c) v += partial[(size_t)c * (256 * BATCH) + idx];
  qsT[idx] = v + bias[s];
}

// Fallback GEMM (used only if workspace too small for split-K).
__global__ __launch_bounds__(256) void k_qsplitT_fb(const float* __restrict__ x,
                                                    const float* __restrict__ W,
                                                    const float* __restrict__ bias,
                                                    float* __restrict__ qsT) {
  const int s = threadIdx.x;
  const int b0 = blockIdx.x * 8;
  if (s >= NSPL) return;
  float acc0[8], acc1[8];
#pragma unroll
  for (int i = 0; i < 8; ++i) { acc0[i] = 0.f; acc1[i] = 0.f; }
#pragma unroll 2
  for (int f = 0; f < 256; ++f) {
    float w0 = W[f * NSPL + s];
    float w1 = W[(f + 256) * NSPL + s];
#pragma unroll
    for (int i = 0; i < 8; ++i) {
      acc0[i] += x[(b0 + i) * FDIM + f] * w0;
      acc1[i] += x[(b0 + i) * FDIM + f + 256] * w1;
    }
  }
  float bs = bias[s];
#pragma unroll
  for (int i = 0; i < 8; ++i) qsT[s * BATCH + b0 + i] = (acc0[i] + acc1[i]) + bs;
}

// ---------------------------------------------------------------------------
// q_node walk (shared by kernels 2 and 4 so bit patterns match)
// ---------------------------------------------------------------------------
__device__ __forceinline__ float qnode_walk(const float* __restrict__ qsT, int n, int b) {
  float q = 1.0f;
  int a = n;
  while (a > 0) {
    int p = (a - 1) >> 1;
    float v = qsT[p * BATCH + b];
    q = fminf(q, (a & 1) ? -v : v);
    a = p;
  }
  return q;
}

// ---------------------------------------------------------------------------
// Kernel 2: g_a[n][c] = 0.5*a_c^2 + 0.5 * sum_b [a_c <= q+0.5] (a_c-(q+0.5))^2
// ---------------------------------------------------------------------------
__global__ __launch_bounds__(256) void k_ga(const float* __restrict__ qsT,
                                            float* __restrict__ ga) {
  const int n = blockIdx.x;
  const int tid = threadIdx.x;
  __shared__ float qs[BATCH];
  __shared__ double part[4][NC];
#pragma unroll
  for (int rep = 0; rep < 2; ++rep) {
    int b = tid + rep * 256;
    qs[b] = qnode_walk(qsT, n, b);
  }
  __syncthreads();
  if (tid < 4 * NC) {
    int c = tid % NC, chunk = tid / NC;
    double ac = 0.05 * (double)c;
    double ssum = 0.0;
    int b0 = chunk * 128;
    for (int b = b0; b < b0 + 128; ++b) {
      float qh = qs[b] + 0.5f;          // f32 add (NumPy scalar promotion keeps f32)
      double dqh = (double)qh;
      if (ac <= dqh) { double d = ac - dqh; ssum += d * d; }
    }
    part[chunk][c] = ssum;
  }
  __syncthreads();
  if (tid < NC) {
    double ac = 0.05 * (double)tid;
    double ssum = ((part[0][tid] + part[1][tid]) + part[2][tid]) + part[3][tid];
    ga[n * NC + tid] = (float)(0.5 * ac * ac + 0.5 * ssum);
  }
}

// ---------------------------------------------------------------------------
// Kernel 3a: initial per-group softmin a_grp0[g] (all k=0 -> g_grp = g_a row).
// ---------------------------------------------------------------------------
__global__ __launch_bounds__(256) void k_agrp0(const float* __restrict__ ga,
                                               double* __restrict__ agrp0) {
  int g = blockIdx.x * 256 + threadIdx.x;
  if (g >= NNOD) return;
  double z[NC], m = -1e300;
#pragma unroll
  for (int c = 0; c < NC; ++c) { z[c] = -100.0 * (double)ga[g * NC + c]; m = fmax(m, z[c]); }
  double S = 0.0;
#pragma unroll
  for (int c = 0; c < NC; ++c) { z[c] = exp(z[c] - m); S += z[c]; }
  double A = 0.0;
#pragma unroll
  for (int c = 0; c < NC; ++c) A += (0.05 * (double)c) * (z[c] / S);
  agrp0[g] = A;
}

// ---------------------------------------------------------------------------
// Kernel 3b: the sequential scan. Single wave (64 threads), all state in LDS.
// anode array is load-bearing: ap must be the SAME BITS the owner lane wrote,
// so merged-node viols are exactly 0.0 (see post-mortem note at top).
// Butterfly stage order 16,8,4,2,1 matches the validated __shfl_xor version
// exactly (same pairing => same f64 sum bits); only the instruction used to
// move lanes changed (DPP/swizzle instead of ds_bpermute).
// ---------------------------------------------------------------------------
__global__ __launch_bounds__(64) void k_scan(const float* __restrict__ ga_g,
                                             const double* __restrict__ agrp0,
                                             double* __restrict__ a_node_out) {
  __shared__ float gaS[NNOD * NC];        // 42924 B
  __shared__ double agrp[512];            // 4096 B
  __shared__ double anode[512];           // 4096 B
  __shared__ float kfS[512];              // 2048 B
  const int lane = threadIdx.x;

  {
    const float4* src = (const float4*)ga_g;
    float4* dst = (float4*)gaS;
    const int n4 = (NNOD * NC) / 4;       // 2682
#pragma unroll 4
    for (int i = lane; i < n4; i += 64) dst[i] = src[i];
    if (lane < (NNOD * NC) - n4 * 4) gaS[n4 * 4 + lane] = ga_g[n4 * 4 + lane];
  }
  for (int i = lane; i < 512; i += 64) {
    agrp[i] = (i < NNOD) ? agrp0[i] : 0.0;
    anode[i] = 0.0;
    kfS[i] = 0.0f;
  }
  __syncthreads();

  int t = 0, p = 0;
  double areg[8];
  int iter = 0;
  for (;;) {
    if (iter > 0) {
      // phase Z: recompute a_grp for groups t (lanes 0..31) and p (lanes 32..63)
      int j = lane >> 5, c = lane & 31;
      int g = j ? p : t;
      double z = -1e300;
      if (c < NC) {
        double acc = (1.0 - (double)kfS[g]) * (double)gaS[g * NC + c];
        int l = 2 * g + 1, r = 2 * g + 2;
        if (l < NNOD) acc = acc + (double)kfS[l] * (double)gaS[l * NC + c];
        if (r < NNOD) acc = acc + (double)kfS[r] * (double)gaS[r * NC + c];
        z = -100.0 * acc;
      }
      // max butterfly, stage order 16,8,4,2,1 (fmax: exact, order-free anyway)
      double m = z;
      m = fmax(m, d_xor16(m));
      m = fmax(m, d_xor8(m));
      m = fmax(m, d_xor4(m));
      m = fmax(m, d_xor2(m));
      m = fmax(m, d_xor1(m));
      double e = (c < NC) ? exp(z - m) : 0.0;
      // S butterfly: same stage order as validated __shfl_xor version
      double S = e;
      S += d_xor16(S);
      S += d_xor8(S);
      S += d_xor4(S);
      S += d_xor2(S);
      S += d_xor1(S);
      double term = (c < NC) ? (0.05 * (double)c) * (e / S) : 0.0;
      term += d_xor16(term);
      term += d_xor8(term);
      term += d_xor4(term);
      term += d_xor2(term);
      term += d_xor1(term);
      if (c == 0) agrp[g] = term;
      __syncthreads();
    }

    // phase N: a_node[n] = k_n*a_grp[par] + (1-k_n)*a_grp[n]
#pragma unroll
    for (int u = 0; u < 8; ++u) {
      int n = lane + (u << 6);
      if (n < NNOD) {
        double kn = (double)kfS[n];
        double agn = agrp[n];
        double an;
        if (n == 0) an = agn;
        else an = kn * agrp[(n - 1) >> 1] + (1.0 - kn) * agn;
        areg[u] = an;
        anode[n] = an;
      }
    }
    __syncthreads();

    // phase V: viol + argmax (first-index tie-break)
    double bv = -1e300; int bi = 0x7fffffff;
#pragma unroll
    for (int u = 0; u < 8; ++u) {
      int n = lane + (u << 6);
      if (n < NNOD) {
        double ap = (n == 0) ? 1.0 : anode[(n - 1) >> 1];
        double vi = areg[u] - ap;
        if (vi > bv) { bv = vi; bi = n; }
      }
    }
    // wave argmax (semilattice: order-free). Stage 32 via shfl, rest DPP/swizzle.
#define AMAX_STAGE(OV, OI)                                                   \
    { double ov = (OV); int oi = (OI);                                       \
      if (ov > bv || (ov == bv && oi < bi)) { bv = ov; bi = oi; } }
    AMAX_STAGE(__shfl_xor(bv, 32, 64), __shfl_xor(bi, 32, 64))
    AMAX_STAGE(d_xor16(bv), i_xor16(bi))
    AMAX_STAGE(d_xor8(bv),  i_xor8(bi))
    AMAX_STAGE(d_xor4(bv),  i_xor4(bi))
    AMAX_STAGE(d_xor2(bv),  i_xor2(bi))
    AMAX_STAGE(d_xor1(bv),  i_xor1(bi))
#undef AMAX_STAGE

    bool cond = (bv <= 1e-8) && (bi > 0);
    if (!cond || iter == 511) break;   // fixed point (exact) or last body
    t = bi; p = (t - 1) >> 1;
    if (lane == 0) kfS[t] += 1.0f;
    __syncthreads();
    ++iter;
  }

#pragma unroll
  for (int u = 0; u < 8; ++u) {
    int n = lane + (u << 6);
    if (n < NNOD) a_node_out[n] = areg[u];
  }
}

// ---------------------------------------------------------------------------
// Kernel 4: out[b][n] = clip(q_node[b,n], 0, a_node[n])
// ---------------------------------------------------------------------------
__global__ __launch_bounds__(256) void k_out(const float* __restrict__ qsT,
                                             const double* __restrict__ a_node,
                                             float* __restrict__ out) {
  int n = blockIdx.x * 256 + threadIdx.x;
  int b = blockIdx.y;
  if (n >= NNOD) return;
  float q = qnode_walk(qsT, n, b);
  double r = fmin(fmax((double)q, 0.0), a_node[n]);
  out[b * NNOD + n] = (float)r;
}

// ---------------------------------------------------------------------------
extern "C" void kernel_launch(void* const* d_in, const int* in_sizes, int n_in,
                              void* d_out, int out_size, void* d_ws, size_t ws_size,
                              hipStream_t stream) {
  (void)in_sizes; (void)n_in; (void)out_size;
  const float* x    = (const float*)d_in[0];
  const float* W    = (const float*)d_in[1];
  const float* bias = (const float*)d_in[2];
  float* out = (float*)d_out;

  char* ws = (char*)d_ws;
  const size_t PART_STRIDE = 256 * BATCH * sizeof(float);   // 524288 B per chunk
  const size_t TAIL = 575488;                                // qsT+ga+agrp0+a_node (padded)

  int n = 8;
  while (n > 1 && (size_t)n * PART_STRIDE + TAIL > ws_size) n >>= 1;
  bool splitk_ok = ((size_t)n * PART_STRIDE + TAIL <= ws_size);

  size_t P = splitk_ok ? (size_t)n * PART_STRIDE : 0;
  float*  qsT    = (float*) (ws + P);
  float*  ga     = (float*) (ws + P + 524288);
  double* agrp0  = (double*)(ws + P + 567296);
  double* a_node = (double*)(ws + P + 571392);

  if (splitk_ok) {
    float* partial = (float*)ws;
    k_qgemm<<<dim3(4, 8, n), dim3(256), 0, stream>>>(x, W, partial, 512 / n);
    k_qreduce<<<dim3(510), dim3(256), 0, stream>>>(partial, bias, qsT, n);
  } else {
    k_qsplitT_fb<<<dim3(64), dim3(256), 0, stream>>>(x, W, bias, qsT);
  }
  k_ga<<<dim3(NNOD), dim3(256), 0, stream>>>(qsT, ga);
  k_agrp0<<<dim3(2), dim3(256), 0, stream>>>(ga, agrp0);
  k_scan<<<dim3(1), dim3(64), 0, stream>>>(ga, agrp0, a_node);
  k_out<<<dim3(2, BATCH), dim3(256), 0, stream>>>(qsT, a_node, out);
}

// Round 6
// 92.861 us; speedup vs baseline: 10.5541x; 10.5541x over previous
//
#include <hip/hip_runtime.h>
#include <hip/hip_bf16.h>
#include <math.h>

// Sizes fixed by the reference setup: B=512, F=512, max_depth=8 -> S=255 splits, N=511 nodes, NC=21.
#define BATCH 512
#define FDIM  512
#define NSPL  255
#define NNOD  511
#define NC    21

// NOTE (round-3/5 post-mortems): the scan's merge dynamics depend on EXACT
// bit-level ties. Two classes of change have empirically broken them (full
// 512-iteration blowup, ~900 us):
//   (1) duplicating f64 blend expressions (ffp-contract divergence, round 3);
//   (2) replacing __shfl_xor butterflies with DPP/swizzle equivalents
//       (round 5 — mechanism unidentified; permutations verified on paper,
//       still broke. DO NOT retry without offline bit-diffing).
// k_scan below is byte-identical to the validated round-2/4 version.
// Safe change classes: memory-path-only changes (same FP op sequence on same
// values), and anything downstream of k_scan (k_out).

// ---------------------------------------------------------------------------
// Kernel 1: tiled split-K GEMM. partial[z][s][b] = sum_{f in chunk z} W[f,s]*x[b,f]
// ---------------------------------------------------------------------------
__global__ __launch_bounds__(256) void k_qgemm(const float* __restrict__ x,
                                               const float* __restrict__ W,
                                               float* __restrict__ partial,
                                               int fpc) {
  __shared__ float Ws[64 * 68];
  __shared__ float xT[64 * 68];
  const int tid = threadIdx.x;
  const int s0 = blockIdx.x * 64;
  const int b0 = blockIdx.y * 64;
  const int f0 = blockIdx.z * fpc;
  const int sx = tid & 15;
  const int by = tid >> 4;
  float acc[4][4];
#pragma unroll
  for (int i = 0; i < 4; ++i)
#pragma unroll
    for (int j = 0; j < 4; ++j) acc[i][j] = 0.f;

  for (int fc = f0; fc < f0 + fpc; fc += 64) {
    {
      int si = tid & 63, fr = tid >> 6;
#pragma unroll
      for (int r = 0; r < 16; ++r) {
        int fi = fr + r * 4;
        int s = s0 + si;
        Ws[fi * 68 + si] = (s < NSPL) ? W[(fc + fi) * NSPL + s] : 0.f;
      }
      int j = tid & 63, ir = tid >> 6;
#pragma unroll
      for (int r = 0; r < 16; ++r) {
        int i = ir + r * 4;
        xT[j * 68 + i] = x[(b0 + i) * FDIM + (fc + j)];
      }
    }
    __syncthreads();
#pragma unroll 8
    for (int f = 0; f < 64; ++f) {
      float4 av = *(const float4*)&Ws[f * 68 + sx * 4];
      float4 xv = *(const float4*)&xT[f * 68 + by * 4];
      const float a4[4] = {av.x, av.y, av.z, av.w};
      const float x4[4] = {xv.x, xv.y, xv.z, xv.w};
#pragma unroll
      for (int i = 0; i < 4; ++i)
#pragma unroll
        for (int j = 0; j < 4; ++j) acc[i][j] += a4[i] * x4[j];
    }
    __syncthreads();
  }

  float* pout = partial + (size_t)blockIdx.z * (256 * BATCH);
#pragma unroll
  for (int i = 0; i < 4; ++i) {
    int s = s0 + sx * 4 + i;
    if (s < NSPL) {
      float4 v = make_float4(acc[i][0], acc[i][1], acc[i][2], acc[i][3]);
      *(float4*)&pout[s * BATCH + b0 + by * 4] = v;
    }
  }
}

// Reduce: qsT[s][b] = (sum_z partial[z][s][b], ascending z) + bias[s]
__global__ __launch_bounds__(256) void k_qreduce(const float* __restrict__ partial,
                                                 const float* __restrict__ bias,
                                                 float* __restrict__ qsT, int n) {
  int idx = blockIdx.x * 256 + threadIdx.x;
  if (idx >= NSPL * BATCH) return;
  int s = idx >> 9;
  float v = 0.f;
  for (int c = 0; c < n; ++c) v += partial[(size_t)c * (256 * BATCH) + idx];
  qsT[idx] = v + bias[s];
}

// Fallback GEMM (used only if workspace too small for split-K).
__global__ __launch_bounds__(256) void k_qsplitT_fb(const float* __restrict__ x,
                                                    const float* __restrict__ W,
                                                    const float* __restrict__ bias,
                                                    float* __restrict__ qsT) {
  const int s = threadIdx.x;
  const int b0 = blockIdx.x * 8;
  if (s >= NSPL) return;
  float acc0[8], acc1[8];
#pragma unroll
  for (int i = 0; i < 8; ++i) { acc0[i] = 0.f; acc1[i] = 0.f; }
#pragma unroll 2
  for (int f = 0; f < 256; ++f) {
    float w0 = W[f * NSPL + s];
    float w1 = W[(f + 256) * NSPL + s];
#pragma unroll
    for (int i = 0; i < 8; ++i) {
      acc0[i] += x[(b0 + i) * FDIM + f] * w0;
      acc1[i] += x[(b0 + i) * FDIM + f + 256] * w1;
    }
  }
  float bs = bias[s];
#pragma unroll
  for (int i = 0; i < 8; ++i) qsT[s * BATCH + b0 + i] = (acc0[i] + acc1[i]) + bs;
}

// ---------------------------------------------------------------------------
// q_node walk (shared by kernels 2 and 4 so bit patterns match)
// ---------------------------------------------------------------------------
__device__ __forceinline__ float qnode_walk(const float* __restrict__ qsT, int n, int b) {
  float q = 1.0f;
  int a = n;
  while (a > 0) {
    int p = (a - 1) >> 1;
    float v = qsT[p * BATCH + b];
    q = fminf(q, (a & 1) ? -v : v);
    a = p;
  }
  return q;
}

// ---------------------------------------------------------------------------
// Kernel 2 (fused): g_a row for node n (byte-identical arithmetic to the
// validated k_ga) + agrp0[n] via the byte-identical serial loop from the
// validated k_agrp0, run by thread 0 on the SAME stored f32 row values.
// ---------------------------------------------------------------------------
__global__ __launch_bounds__(256) void k_ga(const float* __restrict__ qsT,
                                            float* __restrict__ ga,
                                            double* __restrict__ agrp0) {
  const int n = blockIdx.x;
  const int tid = threadIdx.x;
  __shared__ float qs[BATCH];
  __shared__ double part[4][NC];
  __shared__ float gaRow[NC];
#pragma unroll
  for (int rep = 0; rep < 2; ++rep) {
    int b = tid + rep * 256;
    qs[b] = qnode_walk(qsT, n, b);
  }
  __syncthreads();
  if (tid < 4 * NC) {
    int c = tid % NC, chunk = tid / NC;
    double ac = 0.05 * (double)c;
    double ssum = 0.0;
    int b0 = chunk * 128;
    for (int b = b0; b < b0 + 128; ++b) {
      float qh = qs[b] + 0.5f;          // f32 add (NumPy scalar promotion keeps f32)
      double dqh = (double)qh;
      if (ac <= dqh) { double d = ac - dqh; ssum += d * d; }
    }
    part[chunk][c] = ssum;
  }
  __syncthreads();
  if (tid < NC) {
    double ac = 0.05 * (double)tid;
    double ssum = ((part[0][tid] + part[1][tid]) + part[2][tid]) + part[3][tid];
    float gv = (float)(0.5 * ac * ac + 0.5 * ssum);
    ga[n * NC + tid] = gv;
    gaRow[tid] = gv;    // same f32 bits k_agrp0 would have re-read from global
  }
  __syncthreads();
  if (tid == 0) {
    // byte-identical serial softmin from the validated k_agrp0
    double z[NC], m = -1e300;
#pragma unroll
    for (int c = 0; c < NC; ++c) { z[c] = -100.0 * (double)gaRow[c]; m = fmax(m, z[c]); }
    double S = 0.0;
#pragma unroll
    for (int c = 0; c < NC; ++c) { z[c] = exp(z[c] - m); S += z[c]; }
    double A = 0.0;
#pragma unroll
    for (int c = 0; c < NC; ++c) A += (0.05 * (double)c) * (z[c] / S);
    agrp0[n] = A;
  }
}

// ---------------------------------------------------------------------------
// Kernel 3: the sequential scan — BYTE-IDENTICAL to the validated round-2/4
// version. anode array is load-bearing (exact-tie mechanism); __shfl_xor
// butterflies are load-bearing (see note at top). Do not touch.
// ---------------------------------------------------------------------------
__global__ __launch_bounds__(64) void k_scan(const float* __restrict__ ga_g,
                                             const double* __restrict__ agrp0,
                                             double* __restrict__ a_node_out) {
  __shared__ float gaS[NNOD * NC];        // 42924 B
  __shared__ double agrp[512];            // 4096 B
  __shared__ double anode[512];           // 4096 B
  __shared__ float kfS[512];              // 2048 B
  const int lane = threadIdx.x;

  {
    const float4* src = (const float4*)ga_g;
    float4* dst = (float4*)gaS;
    const int n4 = (NNOD * NC) / 4;       // 2682
#pragma unroll 4
    for (int i = lane; i < n4; i += 64) dst[i] = src[i];
    if (lane < (NNOD * NC) - n4 * 4) gaS[n4 * 4 + lane] = ga_g[n4 * 4 + lane];
  }
  for (int i = lane; i < 512; i += 64) {
    agrp[i] = (i < NNOD) ? agrp0[i] : 0.0;
    anode[i] = 0.0;
    kfS[i] = 0.0f;
  }
  __syncthreads();

  int t = 0, p = 0;
  double areg[8];
  int iter = 0;
  for (;;) {
    if (iter > 0) {
      // phase Z: recompute a_grp for groups t (lanes 0..31) and p (lanes 32..63)
      int j = lane >> 5, c = lane & 31;
      int g = j ? p : t;
      double z = -1e300;
      if (c < NC) {
        double acc = (1.0 - (double)kfS[g]) * (double)gaS[g * NC + c];
        int l = 2 * g + 1, r = 2 * g + 2;
        if (l < NNOD) acc = acc + (double)kfS[l] * (double)gaS[l * NC + c];
        if (r < NNOD) acc = acc + (double)kfS[r] * (double)gaS[r * NC + c];
        z = -100.0 * acc;
      }
      double m = z;
#pragma unroll
      for (int off = 16; off >= 1; off >>= 1) m = fmax(m, __shfl_xor(m, off, 32));
      double e = (c < NC) ? exp(z - m) : 0.0;
      double S = e;
#pragma unroll
      for (int off = 16; off >= 1; off >>= 1) S += __shfl_xor(S, off, 32);
      double term = (c < NC) ? (0.05 * (double)c) * (e / S) : 0.0;
#pragma unroll
      for (int off = 16; off >= 1; off >>= 1) term += __shfl_xor(term, off, 32);
      if (c == 0) agrp[g] = term;
      __syncthreads();
    }

    // phase N: a_node[n] = k_n*a_grp[par] + (1-k_n)*a_grp[n]
#pragma unroll
    for (int u = 0; u < 8; ++u) {
      int n = lane + (u << 6);
      if (n < NNOD) {
        double kn = (double)kfS[n];
        double agn = agrp[n];
        double an;
        if (n == 0) an = agn;
        else an = kn * agrp[(n - 1) >> 1] + (1.0 - kn) * agn;
        areg[u] = an;
        anode[n] = an;
      }
    }
    __syncthreads();

    // phase V: viol + argmax (first-index tie-break)
    double bv = -1e300; int bi = 0x7fffffff;
#pragma unroll
    for (int u = 0; u < 8; ++u) {
      int n = lane + (u << 6);
      if (n < NNOD) {
        double ap = (n == 0) ? 1.0 : anode[(n - 1) >> 1];
        double vi = areg[u] - ap;
        if (vi > bv) { bv = vi; bi = n; }
      }
    }
#pragma unroll
    for (int off = 32; off >= 1; off >>= 1) {
      double ov = __shfl_xor(bv, off, 64);
      int oi = __shfl_xor(bi, off, 64);
      if (ov > bv || (ov == bv && oi < bi)) { bv = ov; bi = oi; }
    }

    bool cond = (bv <= 1e-8) && (bi > 0);
    if (!cond || iter == 511) break;   // fixed point (exact) or last body
    t = bi; p = (t - 1) >> 1;
    if (lane == 0) kfS[t] += 1.0f;
    __syncthreads();
    ++iter;
  }

#pragma unroll
  for (int u = 0; u < 8; ++u) {
    int n = lane + (u << 6);
    if (n < NNOD) a_node_out[n] = areg[u];
  }
}

// ---------------------------------------------------------------------------
// Kernel 4: out[b][n] = clip(q_node[b,n], 0, a_node[n]).
// One block per b; qsT column staged in LDS (same f32 values, same fminf
// chain => same bits; and k_out is downstream of all decisions anyway).
// ---------------------------------------------------------------------------
__global__ __launch_bounds__(256) void k_out(const float* __restrict__ qsT,
                                             const double* __restrict__ a_node,
                                             float* __restrict__ out) {
  __shared__ float col[NSPL];
  const int b = blockIdx.x;
  const int tid = threadIdx.x;
  if (tid < NSPL) col[tid] = qsT[tid * BATCH + b];
  __syncthreads();
#pragma unroll
  for (int rep = 0; rep < 2; ++rep) {
    int n = tid + rep * 256;
    if (n < NNOD) {
      float q = 1.0f;
      int a = n;
      while (a > 0) {
        int p = (a - 1) >> 1;
        float v = col[p];
        q = fminf(q, (a & 1) ? -v : v);
        a = p;
      }
      double r = fmin(fmax((double)q, 0.0), a_node[n]);
      out[(size_t)b * NNOD + n] = (float)r;
    }
  }
}

// ---------------------------------------------------------------------------
extern "C" void kernel_launch(void* const* d_in, const int* in_sizes, int n_in,
                              void* d_out, int out_size, void* d_ws, size_t ws_size,
                              hipStream_t stream) {
  (void)in_sizes; (void)n_in; (void)out_size;
  const float* x    = (const float*)d_in[0];
  const float* W    = (const float*)d_in[1];
  const float* bias = (const float*)d_in[2];
  float* out = (float*)d_out;

  char* ws = (char*)d_ws;
  const size_t PART_STRIDE = 256 * BATCH * sizeof(float);   // 524288 B per chunk
  const size_t TAIL = 575488;                                // qsT+ga+agrp0+a_node (padded)

  int n = 8;
  while (n > 1 && (size_t)n * PART_STRIDE + TAIL > ws_size) n >>= 1;
  bool splitk_ok = ((size_t)n * PART_STRIDE + TAIL <= ws_size);

  size_t P = splitk_ok ? (size_t)n * PART_STRIDE : 0;
  float*  qsT    = (float*) (ws + P);
  float*  ga     = (float*) (ws + P + 524288);
  double* agrp0  = (double*)(ws + P + 567296);
  double* a_node = (double*)(ws + P + 571392);

  if (splitk_ok) {
    float* partial = (float*)ws;
    k_qgemm<<<dim3(4, 8, n), dim3(256), 0, stream>>>(x, W, partial, 512 / n);
    k_qreduce<<<dim3(510), dim3(256), 0, stream>>>(partial, bias, qsT, n);
  } else {
    k_qsplitT_fb<<<dim3(64), dim3(256), 0, stream>>>(x, W, bias, qsT);
  }
  k_ga<<<dim3(NNOD), dim3(256), 0, stream>>>(qsT, ga, agrp0);
  k_scan<<<dim3(1), dim3(64), 0, stream>>>(ga, agrp0, a_node);
  k_out<<<dim3(BATCH), dim3(256), 0, stream>>>(qsT, a_node, out);
}